// Round 5
// baseline (1375.115 us; speedup 1.0000x reference)
//
#include <hip/hip_runtime.h>
#include <math.h>

// ws layout (exactly 160 MiB):
//   Ph: _Float16 [9][64][1024][64]  (72 MiB)  "hi" fp16 split of proj
//   Pl: _Float16 [9][64][1024][64]  (72 MiB)  "lo" fp16 split of proj
//   attn: float [1024][4][1024]     (16 MiB)
// w order: 0=q,1=k,2=v,3=q_left,4=k_left,5=q_right,6=k_right,7=q_local,8=k_local
// layout per matrix: [bh][t][d]  EXCEPT w==2 (v) stored transposed [bh][d][t]

typedef _Float16 half8 __attribute__((ext_vector_type(8)));
typedef _Float16 half4v __attribute__((ext_vector_type(4)));
typedef float f32x4 __attribute__((ext_vector_type(4)));

#define MFMA16(A, B, C) __builtin_amdgcn_mfma_f32_16x16x32_f16(A, B, C, 0, 0, 0)

#define SMEM_ATTN ((16 * 1024 + 6 * 128) * 4)

// ---------------- split-fp16 MFMA GEMM: C = A * B^T + bias ----------------
template<int MODE>
__global__ __launch_bounds__(256, 2)
void gemm_mfma(const float* __restrict__ A, const float* __restrict__ B,
               const float* __restrict__ bias, float* __restrict__ C,
               _Float16* __restrict__ Ph, _Float16* __restrict__ Pl,
               int M, int N, int K) {
  __shared__ _Float16 Ah[128 * 64], Al[128 * 64], Bh[128 * 64], Bl[128 * 64];
  const int tid = threadIdx.x;
  const int m0 = blockIdx.x * 128, n0 = blockIdx.y * 128;
  const int wave = tid >> 6, lane = tid & 63;
  const int g2 = lane >> 4, c = lane & 15;
  const int wm = (wave >> 1) * 64, wn = (wave & 1) * 64;

  const int srow = tid >> 1;
  const int shalf = (tid & 1) * 32;
  const int swz = (srow & 7) << 3;
  const float* ap = A + (size_t)(m0 + srow) * K + shalf;
  const float* bp = B + (size_t)(n0 + srow) * K + shalf;

  f32x4 acc[4][4];
#pragma unroll
  for (int i = 0; i < 4; ++i)
#pragma unroll
    for (int j = 0; j < 4; ++j) acc[i][j] = (f32x4){0.f, 0.f, 0.f, 0.f};

  for (int k0 = 0; k0 < K; k0 += 64) {
    float4 av[8], bv[8];
#pragma unroll
    for (int u = 0; u < 8; ++u) {
      av[u] = *(const float4*)(ap + k0 + u * 4);
      bv[u] = *(const float4*)(bp + k0 + u * 4);
    }
    __syncthreads();
#pragma unroll
    for (int u = 0; u < 8; ++u) {
      const int cc = (shalf + u * 4) ^ swz;
      half4v h4a, l4a, h4b, l4b;
      const float* fa = (const float*)&av[u];
      const float* fb = (const float*)&bv[u];
#pragma unroll
      for (int e = 0; e < 4; ++e) {
        _Float16 ha = (_Float16)fa[e];
        h4a[e] = ha; l4a[e] = (_Float16)(fa[e] - (float)ha);
        _Float16 hb = (_Float16)fb[e];
        h4b[e] = hb; l4b[e] = (_Float16)(fb[e] - (float)hb);
      }
      *(half4v*)&Ah[srow * 64 + cc] = h4a;
      *(half4v*)&Al[srow * 64 + cc] = l4a;
      *(half4v*)&Bh[srow * 64 + cc] = h4b;
      *(half4v*)&Bl[srow * 64 + cc] = l4b;
    }
    __syncthreads();
#pragma unroll
    for (int ks = 0; ks < 2; ++ks) {
      const int kb = ks * 32 + 8 * g2;
      half8 a_h[4], a_l[4];
#pragma unroll
      for (int i = 0; i < 4; ++i) {
        const int row = wm + i * 16 + c;
        const int cc = kb ^ ((row & 7) << 3);
        a_h[i] = *(const half8*)&Ah[row * 64 + cc];
        a_l[i] = *(const half8*)&Al[row * 64 + cc];
      }
#pragma unroll
      for (int j = 0; j < 4; ++j) {
        const int rowb = wn + j * 16 + c;
        const int cc = kb ^ ((rowb & 7) << 3);
        const half8 b_h = *(const half8*)&Bh[rowb * 64 + cc];
        const half8 b_l = *(const half8*)&Bl[rowb * 64 + cc];
#pragma unroll
        for (int i = 0; i < 4; ++i) {
          acc[i][j] = MFMA16(a_h[i], b_h, acc[i][j]);
          acc[i][j] = MFMA16(a_h[i], b_l, acc[i][j]);
          acc[i][j] = MFMA16(a_l[i], b_h, acc[i][j]);
        }
      }
    }
  }

#pragma unroll
  for (int j = 0; j < 4; ++j) {
    const int nj = n0 + wn + j * 16 + c;
    const float bz = bias[nj];
    if (MODE == 0) {
#pragma unroll
      for (int i = 0; i < 4; ++i)
#pragma unroll
        for (int q = 0; q < 4; ++q) {
          const int mi = m0 + wm + i * 16 + 4 * g2 + q;
          C[(size_t)mi * N + nj] = acc[i][j][q] + bz;
        }
    } else {
      const int w = nj >> 10, hh = (nj >> 6) & 15, d = nj & 63;
      const float scale = (w == 0 || w == 7) ? 0.125f : 1.0f;
#pragma unroll
      for (int i = 0; i < 4; ++i)
#pragma unroll
        for (int q = 0; q < 4; ++q) {
          const int mi = m0 + wm + i * 16 + 4 * g2 + q;
          const int t = mi >> 2, b2 = mi & 3;
          const size_t bb = ((size_t)w * 64 + (b2 * 16 + hh)) * 65536;
          const size_t idx = (w == 2) ? bb + (size_t)d * 1024 + t
                                      : bb + (size_t)t * 64 + d;
          const float v = (acc[i][j][q] + bz) * scale;
          const _Float16 h16 = (_Float16)v;
          Ph[idx] = h16;
          Pl[idx] = (_Float16)(v - (float)h16);
        }
    }
  }
}

// ---------------- fused attention: scores in registers, mask via LDS ----------------
// grid (64 tblocks, 64 bh), block 512 (8 waves), dynamic LDS 68.6 KB -> 2 WG/CU
__global__ __launch_bounds__(512, 2)
void attn_mfma(const _Float16* __restrict__ Ph, const _Float16* __restrict__ Pl,
               float* __restrict__ attnOut) {
  extern __shared__ float smem[];
  float* sP = smem;                  // [16][1024] fp32, XOR-swizzled
  float* sRed = smem + 16 * 1024;    // [6][16][8] scratch
  const int t0 = blockIdx.x << 4;
  const int bh = blockIdx.y;
  const int tid = threadIdx.x;
  const int wave = tid >> 6, lane = tid & 63;
  const int g2 = lane >> 4, c = lane & 15;
  const int sbase = wave << 7;
  // reg layout: v[m][q] = S[4*g2+q][sbase + 16*m + c]

  // swizzled float index: byte ^= ((row&7)<<4); XOR touches byte bits 4..6 only
  auto pidx = [&](int row, int col) { return row * 1024 + (col ^ ((row & 7) << 2)); };

  auto mbase = [&](int w) { return ((size_t)w * 64 + bh) * 65536; };

  // 8 tiles of 16 cols; only one tile's B-fragments live at a time
  auto scores = [&](int wq, int wk, f32x4* out) {
    const _Float16* qh = Ph + mbase(wq) + (size_t)(t0 + c) * 64 + 8 * g2;
    const _Float16* ql = Pl + mbase(wq) + (size_t)(t0 + c) * 64 + 8 * g2;
    const half8 ah0 = *(const half8*)qh, ah1 = *(const half8*)(qh + 32);
    const half8 al0 = *(const half8*)ql, al1 = *(const half8*)(ql + 32);
    const _Float16* kbh = Ph + mbase(wk);
    const _Float16* kbl = Pl + mbase(wk);
#pragma unroll
    for (int tp = 0; tp < 8; ++tp) {
      const int s0 = sbase + tp * 16;
      const _Float16* kh = kbh + (size_t)(s0 + c) * 64 + 8 * g2;
      const _Float16* kl = kbl + (size_t)(s0 + c) * 64 + 8 * g2;
      const half8 bh0 = *(const half8*)kh, bh1 = *(const half8*)(kh + 32);
      const half8 bl0 = *(const half8*)kl, bl1 = *(const half8*)(kl + 32);
      f32x4 a = {0.f, 0.f, 0.f, 0.f};
      a = MFMA16(ah0, bh0, a);
      a = MFMA16(ah1, bh1, a);
      a = MFMA16(ah0, bl0, a);
      a = MFMA16(ah1, bl1, a);
      a = MFMA16(al0, bh0, a);
      a = MFMA16(al1, bh1, a);
      out[tp] = a;
    }
  };

  auto grp_max = [&](const f32x4* v) {
    f32x4 m = v[0];
#pragma unroll
    for (int i = 1; i < 8; ++i)
#pragma unroll
      for (int q = 0; q < 4; ++q) m[q] = fmaxf(m[q], v[i][q]);
#pragma unroll
    for (int off = 1; off < 16; off <<= 1)
#pragma unroll
      for (int q = 0; q < 4; ++q) m[q] = fmaxf(m[q], __shfl_xor(m[q], off, 64));
    return m;
  };
  auto grp_sum = [&](f32x4 s) {
#pragma unroll
    for (int off = 1; off < 16; off <<= 1)
#pragma unroll
      for (int q = 0; q < 4; ++q) s[q] += __shfl_xor(s[q], off, 64);
    return s;
  };
  auto put = [&](int slot, f32x4 val) {
    if (c < 4) {
      const float x = (c == 0) ? val[0] : (c == 1) ? val[1] : (c == 2) ? val[2] : val[3];
      sRed[slot * 128 + (4 * g2 + c) * 8 + wave] = x;
    }
  };
  auto get_max = [&](int slot) {
    f32x4 r;
#pragma unroll
    for (int q = 0; q < 4; ++q) {
      const float* p = sRed + slot * 128 + (4 * g2 + q) * 8;
      r[q] = fmaxf(fmaxf(fmaxf(p[0], p[1]), fmaxf(p[2], p[3])),
                   fmaxf(fmaxf(p[4], p[5]), fmaxf(p[6], p[7])));
    }
    return r;
  };
  auto get_sum = [&](int slot) {
    f32x4 r;
#pragma unroll
    for (int q = 0; q < 4; ++q) {
      const float* p = sRed + slot * 128 + (4 * g2 + q) * 8;
      r[q] = ((p[0] + p[1]) + (p[2] + p[3])) + ((p[4] + p[5]) + (p[6] + p[7]));
    }
    return r;
  };
  auto get_pref = [&](int slot) {
    f32x4 r = {0.f, 0.f, 0.f, 0.f};
#pragma unroll
    for (int q = 0; q < 4; ++q) {
      const float* p = sRed + slot * 128 + (4 * g2 + q) * 8;
      float s = 0.f;
      for (int w = 0; w < wave; ++w) s += p[w];
      r[q] = s;
    }
    return r;
  };
  auto scan = [&](f32x4* v, int slot) {
    f32x4 carry = {0.f, 0.f, 0.f, 0.f};
#pragma unroll
    for (int m = 0; m < 8; ++m) {
      f32x4 x = v[m];
#pragma unroll
      for (int off = 1; off < 16; off <<= 1)
#pragma unroll
        for (int q = 0; q < 4; ++q) {
          const float u = __shfl_up(x[q], off, 64);
          if (c >= off) x[q] += u;
        }
      x += carry;
#pragma unroll
      for (int q = 0; q < 4; ++q) carry[q] = __shfl(x[q], (lane & 48) | 15, 64);
      v[m] = x;
    }
    put(slot, carry);
  };

  // ================= phase A: left/right -> local_mask -> sP ============
  {
    f32x4 rv[8], lv[8];
    scores(5, 6, rv);                 // right
    scores(3, 4, lv);                 // left
    put(0, grp_max(rv));
    put(1, grp_max(lv));
    __syncthreads();                  // B1
    const f32x4 MR = get_max(0), ML = get_max(1);
    f32x4 sR = {0.f, 0.f, 0.f, 0.f}, sL = {0.f, 0.f, 0.f, 0.f};
#pragma unroll
    for (int m = 0; m < 8; ++m) {
#pragma unroll
      for (int q = 0; q < 4; ++q) {
        rv[m][q] = expf(rv[m][q] - MR[q]);
        lv[m][q] = expf(lv[m][q] - ML[q]);
      }
      sR += rv[m];
      sL += lv[m];
    }
    put(2, grp_sum(sR));
    put(3, grp_sum(sL));
    __syncthreads();                // B2
    const f32x4 SR = get_sum(2), SL = get_sum(3);
    f32x4 iR, iL;
#pragma unroll
    for (int q = 0; q < 4; ++q) { iR[q] = 1.f / SR[q]; iL[q] = 1.f / SL[q]; }
#pragma unroll
    for (int m = 0; m < 8; ++m) { rv[m] *= iR; lv[m] *= iL; }
    scan(rv, 4);
    scan(lv, 5);
    __syncthreads();                // B3
    const f32x4 pR = get_pref(4), pL = get_pref(5);
#pragma unroll
    for (int m = 0; m < 8; ++m) { rv[m] += pR; lv[m] += pL; }
    // mask = af*(1-bfx) + (1-afx)*bf   (normalized totals == 1)
#pragma unroll
    for (int m = 7; m >= 0; --m) {
      f32x4 afx, bfx;
#pragma unroll
      for (int q = 0; q < 4; ++q) {
        const float ua = __shfl_up(lv[m][q], 1, 64);
        const float ub = __shfl_up(rv[m][q], 1, 64);
        const float la = (m > 0) ? __shfl(lv[m - 1][q], (lane & 48) | 15, 64) : pL[q];
        const float lb = (m > 0) ? __shfl(rv[m - 1][q], (lane & 48) | 15, 64) : pR[q];
        afx[q] = (c == 0) ? la : ua;
        bfx[q] = (c == 0) ? lb : ub;
      }
      lv[m] = lv[m] * (1.f - bfx) + (1.f - afx) * rv[m];
    }
    // spill mask to LDS (same lane re-reads it later; no barrier needed)
#pragma unroll
    for (int m = 0; m < 8; ++m)
#pragma unroll
      for (int q = 0; q < 4; ++q)
        sP[pidx(4 * g2 + q, sbase + 16 * m + c)] = lv[m][q];
  }

  // ================= phase B: global (regs) + local*mask -> sP ============
  {
    f32x4 gv[8];
    scores(0, 1, gv);               // global
    put(0, grp_max(gv));
    __syncthreads();                // B4
    const f32x4 MG = get_max(0);
    f32x4 sG = {0.f, 0.f, 0.f, 0.f};
#pragma unroll
    for (int m = 0; m < 8; ++m) {
#pragma unroll
      for (int q = 0; q < 4; ++q) gv[m][q] = expf(gv[m][q] - MG[q]);
      sG += gv[m];
    }
    put(2, grp_sum(sG));
    __syncthreads();                // B5
    const f32x4 SG = get_sum(2);
    f32x4 iG;
#pragma unroll
    for (int q = 0; q < 4; ++q) iG[q] = 0.5f / SG[q];

    f32x4 ov[8];
    scores(7, 8, ov);               // local
    put(1, grp_max(ov));
    __syncthreads();                // B6
    const f32x4 MO = get_max(1);
    f32x4 sO = {0.f, 0.f, 0.f, 0.f};
#pragma unroll
    for (int m = 0; m < 8; ++m) {
#pragma unroll
      for (int q = 0; q < 4; ++q)
        ov[m][q] = expf(ov[m][q] - MO[q]) * sP[pidx(4 * g2 + q, sbase + 16 * m + c)];
      sO += ov[m];
    }
    put(3, grp_sum(sO));
    __syncthreads();                // B7
    const f32x4 SO = get_sum(3);
    f32x4 iO;
#pragma unroll
    for (int q = 0; q < 4; ++q) iO[q] = 0.5f / SO[q];
#pragma unroll
    for (int m = 0; m < 8; ++m)
#pragma unroll
      for (int q = 0; q < 4; ++q)
        sP[pidx(4 * g2 + q, sbase + 16 * m + c)] =
            gv[m][q] * iG[q] + ov[m][q] * iO[q];
  }
  __syncthreads();                  // B8: P complete

  // ================= PV via MFMA =================
  f32x4 cacc[4];
#pragma unroll
  for (int dt = 0; dt < 4; ++dt) cacc[dt] = (f32x4){0.f, 0.f, 0.f, 0.f};
  {
    const _Float16* vbh = Ph + mbase(2);
    const _Float16* vbl = Pl + mbase(2);
#pragma unroll
    for (int kk = 0; kk < 4; ++kk) {
      const int sk = sbase + kk * 32;
      float pv[8];
      *(float4*)&pv[0] = *(const float4*)&sP[pidx(c, sk + 8 * g2)];
      *(float4*)&pv[4] = *(const float4*)&sP[pidx(c, sk + 8 * g2 + 4)];
      half8 pah, pal;
#pragma unroll
      for (int j = 0; j < 8; ++j) {
        const _Float16 h16 = (_Float16)pv[j];
        pah[j] = h16;
        pal[j] = (_Float16)(pv[j] - (float)h16);
      }
#pragma unroll
      for (int dt = 0; dt < 4; ++dt) {
        const _Float16* vh = vbh + (size_t)(dt * 16 + c) * 1024 + sk + 8 * g2;
        const _Float16* vl = vbl + (size_t)(dt * 16 + c) * 1024 + sk + 8 * g2;
        const half8 bh8 = *(const half8*)vh;
        const half8 bl8 = *(const half8*)vl;
        cacc[dt] = MFMA16(pah, bh8, cacc[dt]);
        cacc[dt] = MFMA16(pah, bl8, cacc[dt]);
        cacc[dt] = MFMA16(pal, bh8, cacc[dt]);
      }
    }
  }
  __syncthreads();                  // all P reads done before reuse
#pragma unroll
  for (int dt = 0; dt < 4; ++dt)
#pragma unroll
    for (int q = 0; q < 4; ++q)
      sP[(wave * 16 + 4 * g2 + q) * 65 + dt * 16 + c] = cacc[dt][q];
  __syncthreads();
  {
    const int b2 = bh >> 4, hh = bh & 15;
    for (int o = tid; o < 1024; o += 512) {
      const int r = o >> 6, d = o & 63;
      float a = 0.f;
#pragma unroll
      for (int w = 0; w < 8; ++w) a += sP[(w * 16 + r) * 65 + d];
      attnOut[((size_t)(t0 + r) * 4 + b2) * 1024 + hh * 64 + d] = a;
    }
  }
}

extern "C" void kernel_launch(void* const* d_in, const int* in_sizes, int n_in,
                              void* d_out, int out_size, void* d_ws, size_t ws_size,
                              hipStream_t stream) {
  const float* x     = (const float*)d_in[0];
  const float* w_in  = (const float*)d_in[1];
  const float* b_in  = (const float*)d_in[2];
  const float* w_out = (const float*)d_in[3];
  const float* b_out = (const float*)d_in[4];

  const size_t NP = (size_t)9 * 64 * 1024 * 64;
  _Float16* Ph = (_Float16*)d_ws;
  _Float16* Pl = Ph + NP;
  float* attn = (float*)(Pl + NP);

  (void)hipFuncSetAttribute((const void*)attn_mfma,
                            hipFuncAttributeMaxDynamicSharedMemorySize,
                            SMEM_ATTN);

  // proj = x @ w_in^T + b_in -> fp16 h/l split, head-major; v transposed
  gemm_mfma<1><<<dim3(32, 72), 256, 0, stream>>>(x, w_in, b_in, nullptr, Ph, Pl, 4096, 9216, 1024);
  // fused attention
  attn_mfma<<<dim3(64, 64), 512, SMEM_ATTN, stream>>>(Ph, Pl, attn);
  // out = attn @ w_out^T + b_out
  gemm_mfma<0><<<dim3(32, 8), 256, 0, stream>>>(attn, w_out, b_out, (float*)d_out, nullptr, nullptr, 4096, 1024, 1024);
}

// Round 6
// 1223.654 us; speedup vs baseline: 1.1238x; 1.1238x over previous
//
#include <hip/hip_runtime.h>
#include <math.h>

// ws layout (exactly 160 MiB):
//   Ph: _Float16 [9][64][1024][64]  (72 MiB)  "hi" fp16 split of proj
//   Pl: _Float16 [9][64][1024][64]  (72 MiB)  "lo" fp16 split of proj
//   attn: float [1024][4][1024]     (16 MiB)
// w order: 0=q,1=k,2=v,3=q_left,4=k_left,5=q_right,6=k_right,7=q_local,8=k_local
// layout per matrix: [bh][t][d]  EXCEPT w==2 (v) stored transposed [bh][d][t]

typedef _Float16 half8 __attribute__((ext_vector_type(8)));
typedef _Float16 half4v __attribute__((ext_vector_type(4)));
typedef float f32x4 __attribute__((ext_vector_type(4)));

#define MFMA16(A, B, C) __builtin_amdgcn_mfma_f32_16x16x32_f16(A, B, C, 0, 0, 0)

#define SMEM_ATTN ((16 * 1024 + 2 * 128) * 4)

// ---------------- split-fp16 MFMA GEMM: C = A * B^T + bias ----------------
template<int MODE>
__global__ __launch_bounds__(256, 2)
void gemm_mfma(const float* __restrict__ A, const float* __restrict__ B,
               const float* __restrict__ bias, float* __restrict__ C,
               _Float16* __restrict__ Ph, _Float16* __restrict__ Pl,
               int M, int N, int K) {
  __shared__ _Float16 Ah[128 * 64], Al[128 * 64], Bh[128 * 64], Bl[128 * 64];
  const int tid = threadIdx.x;
  const int m0 = blockIdx.x * 128, n0 = blockIdx.y * 128;
  const int wave = tid >> 6, lane = tid & 63;
  const int g2 = lane >> 4, c = lane & 15;
  const int wm = (wave >> 1) * 64, wn = (wave & 1) * 64;

  const int srow = tid >> 1;
  const int shalf = (tid & 1) * 32;
  const int swz = (srow & 7) << 3;
  const float* ap = A + (size_t)(m0 + srow) * K + shalf;
  const float* bp = B + (size_t)(n0 + srow) * K + shalf;

  f32x4 acc[4][4];
#pragma unroll
  for (int i = 0; i < 4; ++i)
#pragma unroll
    for (int j = 0; j < 4; ++j) acc[i][j] = (f32x4){0.f, 0.f, 0.f, 0.f};

  for (int k0 = 0; k0 < K; k0 += 64) {
    float4 av[8], bv[8];
#pragma unroll
    for (int u = 0; u < 8; ++u) {
      av[u] = *(const float4*)(ap + k0 + u * 4);
      bv[u] = *(const float4*)(bp + k0 + u * 4);
    }
    __syncthreads();
#pragma unroll
    for (int u = 0; u < 8; ++u) {
      const int cc = (shalf + u * 4) ^ swz;
      half4v h4a, l4a, h4b, l4b;
      const float* fa = (const float*)&av[u];
      const float* fb = (const float*)&bv[u];
#pragma unroll
      for (int e = 0; e < 4; ++e) {
        _Float16 ha = (_Float16)fa[e];
        h4a[e] = ha; l4a[e] = (_Float16)(fa[e] - (float)ha);
        _Float16 hb = (_Float16)fb[e];
        h4b[e] = hb; l4b[e] = (_Float16)(fb[e] - (float)hb);
      }
      *(half4v*)&Ah[srow * 64 + cc] = h4a;
      *(half4v*)&Al[srow * 64 + cc] = l4a;
      *(half4v*)&Bh[srow * 64 + cc] = h4b;
      *(half4v*)&Bl[srow * 64 + cc] = l4b;
    }
    __syncthreads();
#pragma unroll
    for (int ks = 0; ks < 2; ++ks) {
      const int kb = ks * 32 + 8 * g2;
      half8 a_h[4], a_l[4];
#pragma unroll
      for (int i = 0; i < 4; ++i) {
        const int row = wm + i * 16 + c;
        const int cc = kb ^ ((row & 7) << 3);
        a_h[i] = *(const half8*)&Ah[row * 64 + cc];
        a_l[i] = *(const half8*)&Al[row * 64 + cc];
      }
#pragma unroll
      for (int j = 0; j < 4; ++j) {
        const int rowb = wn + j * 16 + c;
        const int cc = kb ^ ((rowb & 7) << 3);
        const half8 b_h = *(const half8*)&Bh[rowb * 64 + cc];
        const half8 b_l = *(const half8*)&Bl[rowb * 64 + cc];
#pragma unroll
        for (int i = 0; i < 4; ++i) {
          acc[i][j] = MFMA16(a_h[i], b_h, acc[i][j]);
          acc[i][j] = MFMA16(a_h[i], b_l, acc[i][j]);
          acc[i][j] = MFMA16(a_l[i], b_h, acc[i][j]);
        }
      }
    }
  }

#pragma unroll
  for (int j = 0; j < 4; ++j) {
    const int nj = n0 + wn + j * 16 + c;
    const float bz = bias[nj];
    if (MODE == 0) {
#pragma unroll
      for (int i = 0; i < 4; ++i)
#pragma unroll
        for (int q = 0; q < 4; ++q) {
          const int mi = m0 + wm + i * 16 + 4 * g2 + q;
          C[(size_t)mi * N + nj] = acc[i][j][q] + bz;
        }
    } else {
      const int w = nj >> 10, hh = (nj >> 6) & 15, d = nj & 63;
      const float scale = (w == 0 || w == 7) ? 0.125f : 1.0f;
#pragma unroll
      for (int i = 0; i < 4; ++i)
#pragma unroll
        for (int q = 0; q < 4; ++q) {
          const int mi = m0 + wm + i * 16 + 4 * g2 + q;
          const int t = mi >> 2, b2 = mi & 3;
          const size_t bb = ((size_t)w * 64 + (b2 * 16 + hh)) * 65536;
          const size_t idx = (w == 2) ? bb + (size_t)d * 1024 + t
                                      : bb + (size_t)t * 64 + d;
          const float v = (acc[i][j][q] + bz) * scale;
          const _Float16 h16 = (_Float16)v;
          Ph[idx] = h16;
          Pl[idx] = (_Float16)(v - (float)h16);
        }
    }
  }
}

// ---------------- fused attention: sequential phases, 6 barriers ----------------
// grid 4096 (XCD-chunked), block 512 (8 waves), dynamic LDS 66560 B -> 2 WG/CU
__global__ __launch_bounds__(512, 2)
void attn_mfma(const _Float16* __restrict__ Ph, const _Float16* __restrict__ Pl,
               float* __restrict__ attnOut) {
  extern __shared__ float smem[];
  float* sP = smem;                  // [16][1024] fp32, XOR-swizzled
  float* sRed = smem + 16 * 1024;    // [2][16][8] wave-partial sums
  // XCD-chunked mapping: dispatch is round-robin over 8 XCDs; make each XCD
  // own a contiguous range of (bh, tblock) so K/V panels stay in its L2.
  const int flat = blockIdx.x;
  const int nf = (flat & 7) * 512 + (flat >> 3);
  const int bh = nf >> 6;
  const int t0 = (nf & 63) << 4;
  const int tid = threadIdx.x;
  const int wave = tid >> 6, lane = tid & 63;
  const int g2 = lane >> 4, c = lane & 15;
  const int sbase = wave << 7;
  // reg layout: v[m][q] = S[4*g2+q][sbase + 16*m + c]

  // swizzled float index: byte ^= ((row&7)<<4)
  auto pidx = [&](int row, int col) { return row * 1024 + (col ^ ((row & 7) << 2)); };
  auto mbase = [&](int w) { return ((size_t)w * 64 + bh) * 65536; };

  auto scores = [&](int wq, int wk, f32x4* out) {
    const _Float16* qh = Ph + mbase(wq) + (size_t)(t0 + c) * 64 + 8 * g2;
    const _Float16* ql = Pl + mbase(wq) + (size_t)(t0 + c) * 64 + 8 * g2;
    const half8 ah0 = *(const half8*)qh, ah1 = *(const half8*)(qh + 32);
    const half8 al0 = *(const half8*)ql, al1 = *(const half8*)(ql + 32);
    const _Float16* kbh = Ph + mbase(wk);
    const _Float16* kbl = Pl + mbase(wk);
#pragma unroll
    for (int tp = 0; tp < 8; ++tp) {
      const int s0 = sbase + tp * 16;
      const _Float16* kh = kbh + (size_t)(s0 + c) * 64 + 8 * g2;
      const _Float16* kl = kbl + (size_t)(s0 + c) * 64 + 8 * g2;
      const half8 bh0 = *(const half8*)kh, bh1 = *(const half8*)(kh + 32);
      const half8 bl0 = *(const half8*)kl, bl1 = *(const half8*)(kl + 32);
      f32x4 a = {0.f, 0.f, 0.f, 0.f};
      a = MFMA16(ah0, bh0, a);
      a = MFMA16(ah1, bh1, a);
      a = MFMA16(ah0, bl0, a);
      a = MFMA16(ah1, bl1, a);
      a = MFMA16(al0, bh0, a);
      a = MFMA16(al1, bh1, a);
      out[tp] = a;
    }
  };

  // write wave-partial per-row values to slot; read combined after barrier
  auto put = [&](int slot, f32x4 val) {
    if (c < 4) {
      const float x = (c == 0) ? val[0] : (c == 1) ? val[1] : (c == 2) ? val[2] : val[3];
      sRed[slot * 128 + (4 * g2 + c) * 8 + wave] = x;
    }
  };
  // returns total S; pref = sum over waves < this wave
  auto get_sum_pref = [&](int slot, f32x4& pref) {
    f32x4 S = {0.f, 0.f, 0.f, 0.f};
    pref = (f32x4){0.f, 0.f, 0.f, 0.f};
#pragma unroll
    for (int q = 0; q < 4; ++q) {
      const float* p = sRed + slot * 128 + (4 * g2 + q) * 8;
#pragma unroll
      for (int w = 0; w < 8; ++w) {
        const float t = p[w];
        S[q] += t;
        if (w < wave) pref[q] += t;
      }
    }
    return S;
  };
  // exp in place, then segmented inclusive scan along s; returns wave total
  auto exp_scan = [&](f32x4* v) {
    f32x4 carry = {0.f, 0.f, 0.f, 0.f};
#pragma unroll
    for (int m = 0; m < 8; ++m) {
      f32x4 x;
#pragma unroll
      for (int q = 0; q < 4; ++q) x[q] = __expf(v[m][q]);
#pragma unroll
      for (int off = 1; off < 16; off <<= 1)
#pragma unroll
        for (int q = 0; q < 4; ++q) {
          const float u = __shfl_up(x[q], off, 64);
          if (c >= off) x[q] += u;
        }
      x += carry;
#pragma unroll
      for (int q = 0; q < 4; ++q) carry[q] = __shfl(x[q], (lane & 48) | 15, 64);
      v[m] = x;
    }
    return carry;
  };
  auto exp_sum16 = [&](f32x4* v) {   // exp in place + 16-lane row sum
    f32x4 s = {0.f, 0.f, 0.f, 0.f};
#pragma unroll
    for (int m = 0; m < 8; ++m) {
#pragma unroll
      for (int q = 0; q < 4; ++q) v[m][q] = __expf(v[m][q]);
      s += v[m];
    }
#pragma unroll
    for (int off = 1; off < 16; off <<= 1)
#pragma unroll
      for (int q = 0; q < 4; ++q) s[q] += __shfl_xor(s[q], off, 64);
    return s;
  };

  f32x4 bndL;   // normalized exclusive left-cumsum at this wave's slice start

  // ===== phase 1: LEFT -> normalized inclusive cumsum into sP =====
  {
    f32x4 ev[8];
    scores(3, 4, ev);
    put(0, exp_scan(ev));
    __syncthreads();                          // B1
    f32x4 pref;
    const f32x4 S = get_sum_pref(0, pref);
    f32x4 inv;
#pragma unroll
    for (int q = 0; q < 4; ++q) inv[q] = 1.f / S[q];
    bndL = pref * inv;
#pragma unroll
    for (int m = 0; m < 8; ++m) {
      const f32x4 af = (ev[m] + pref) * inv;
#pragma unroll
      for (int q = 0; q < 4; ++q)
        sP[pidx(4 * g2 + q, sbase + 16 * m + c)] = af[q];
    }
  }

  // ===== phase 2: RIGHT -> local_mask into sP (in place, descending m) =====
  {
    f32x4 ev[8];
    scores(5, 6, ev);
    put(1, exp_scan(ev));
    __syncthreads();                          // B2
    f32x4 pref;
    const f32x4 S = get_sum_pref(1, pref);
    f32x4 inv;
#pragma unroll
    for (int q = 0; q < 4; ++q) inv[q] = 1.f / S[q];
    const f32x4 prefR = pref * inv;
#pragma unroll
    for (int m = 0; m < 8; ++m) ev[m] = (ev[m] + pref) * inv;   // bf inclusive
    // mask = af*(1-bfx) + (1-afe)*bf ; descending m keeps reads ahead of writes
#pragma unroll
    for (int m = 7; m >= 0; --m) {
      f32x4 bfx, afi, afe;
#pragma unroll
      for (int q = 0; q < 4; ++q) {
        const float u = __shfl_up(ev[m][q], 1, 64);
        const float lp = (m > 0) ? __shfl(ev[m - 1][q], (lane & 48) | 15, 64) : prefR[q];
        bfx[q] = (c == 0) ? lp : u;
        const int row = 4 * g2 + q, col = sbase + 16 * m + c;
        afi[q] = sP[pidx(row, col)];
        afe[q] = (c == 0 && m == 0) ? bndL[q] : sP[pidx(row, col - 1)];
      }
      const f32x4 mask = afi * (1.f - bfx) + (1.f - afe) * ev[m];
#pragma unroll
      for (int q = 0; q < 4; ++q)
        sP[pidx(4 * g2 + q, sbase + 16 * m + c)] = mask[q];
    }
  }

  // ===== phase 3: LOCAL -> P_local*0.5 into sP (consumes mask) =====
  {
    f32x4 ov[8];
    scores(7, 8, ov);
    f32x4 s = {0.f, 0.f, 0.f, 0.f};
#pragma unroll
    for (int m = 0; m < 8; ++m) {
#pragma unroll
      for (int q = 0; q < 4; ++q)
        ov[m][q] = __expf(ov[m][q]) * sP[pidx(4 * g2 + q, sbase + 16 * m + c)];
      s += ov[m];
    }
#pragma unroll
    for (int off = 1; off < 16; off <<= 1)
#pragma unroll
      for (int q = 0; q < 4; ++q) s[q] += __shfl_xor(s[q], off, 64);
    put(0, s);
    __syncthreads();                          // B3
    f32x4 pref;
    const f32x4 S = get_sum_pref(0, pref);
    f32x4 sc;
#pragma unroll
    for (int q = 0; q < 4; ++q) sc[q] = 0.5f / S[q];
#pragma unroll
    for (int m = 0; m < 8; ++m)
#pragma unroll
      for (int q = 0; q < 4; ++q)
        sP[pidx(4 * g2 + q, sbase + 16 * m + c)] = ov[m][q] * sc[q];
  }

  // ===== phase 4: GLOBAL -> += P_global*0.5 =====
  {
    f32x4 gv[8];
    scores(0, 1, gv);
    put(1, exp_sum16(gv));
    __syncthreads();                          // B4
    f32x4 pref;
    const f32x4 S = get_sum_pref(1, pref);
    f32x4 sc;
#pragma unroll
    for (int q = 0; q < 4; ++q) sc[q] = 0.5f / S[q];
#pragma unroll
    for (int m = 0; m < 8; ++m)
#pragma unroll
      for (int q = 0; q < 4; ++q)
        sP[pidx(4 * g2 + q, sbase + 16 * m + c)] += gv[m][q] * sc[q];
  }
  // no barrier: each wave's P slice is wave-private (written and read by itself)

  // ===== PV via MFMA =====
  f32x4 cacc[4];
#pragma unroll
  for (int dt = 0; dt < 4; ++dt) cacc[dt] = (f32x4){0.f, 0.f, 0.f, 0.f};
  {
    const _Float16* vbh = Ph + mbase(2);
    const _Float16* vbl = Pl + mbase(2);
#pragma unroll
    for (int kk = 0; kk < 4; ++kk) {
      const int sk = sbase + kk * 32;
      float pv[8];
      *(float4*)&pv[0] = *(const float4*)&sP[pidx(c, sk + 8 * g2)];
      *(float4*)&pv[4] = *(const float4*)&sP[pidx(c, sk + 8 * g2 + 4)];
      half8 pah, pal;
#pragma unroll
      for (int j = 0; j < 8; ++j) {
        const _Float16 h16 = (_Float16)pv[j];
        pah[j] = h16;
        pal[j] = (_Float16)(pv[j] - (float)h16);
      }
#pragma unroll
      for (int dt = 0; dt < 4; ++dt) {
        const _Float16* vh = vbh + (size_t)(dt * 16 + c) * 1024 + sk + 8 * g2;
        const _Float16* vl = vbl + (size_t)(dt * 16 + c) * 1024 + sk + 8 * g2;
        const half8 bh8 = *(const half8*)vh;
        const half8 bl8 = *(const half8*)vl;
        cacc[dt] = MFMA16(pah, bh8, cacc[dt]);
        cacc[dt] = MFMA16(pah, bl8, cacc[dt]);
        cacc[dt] = MFMA16(pal, bh8, cacc[dt]);
      }
    }
  }
  __syncthreads();                  // B5: all PV reads done before sP reuse
#pragma unroll
  for (int dt = 0; dt < 4; ++dt)
#pragma unroll
    for (int q = 0; q < 4; ++q)
      sP[(wave * 16 + 4 * g2 + q) * 65 + dt * 16 + c] = cacc[dt][q];
  __syncthreads();                  // B6
  {
    const int b2 = bh >> 4, hh = bh & 15;
    for (int o = tid; o < 1024; o += 512) {
      const int r = o >> 6, d = o & 63;
      float a = 0.f;
#pragma unroll
      for (int w = 0; w < 8; ++w) a += sP[(w * 16 + r) * 65 + d];
      attnOut[((size_t)(t0 + r) * 4 + b2) * 1024 + hh * 64 + d] = a;
    }
  }
}

extern "C" void kernel_launch(void* const* d_in, const int* in_sizes, int n_in,
                              void* d_out, int out_size, void* d_ws, size_t ws_size,
                              hipStream_t stream) {
  const float* x     = (const float*)d_in[0];
  const float* w_in  = (const float*)d_in[1];
  const float* b_in  = (const float*)d_in[2];
  const float* w_out = (const float*)d_in[3];
  const float* b_out = (const float*)d_in[4];

  const size_t NP = (size_t)9 * 64 * 1024 * 64;
  _Float16* Ph = (_Float16*)d_ws;
  _Float16* Pl = Ph + NP;
  float* attn = (float*)(Pl + NP);

  (void)hipFuncSetAttribute((const void*)attn_mfma,
                            hipFuncAttributeMaxDynamicSharedMemorySize,
                            SMEM_ATTN);

  // proj = x @ w_in^T + b_in -> fp16 h/l split, head-major; v transposed
  gemm_mfma<1><<<dim3(32, 72), 256, 0, stream>>>(x, w_in, b_in, nullptr, Ph, Pl, 4096, 9216, 1024);
  // fused attention
  attn_mfma<<<4096, 512, SMEM_ATTN, stream>>>(Ph, Pl, attn);
  // out = attn @ w_out^T + b_out
  gemm_mfma<0><<<dim3(32, 8), 256, 0, stream>>>(attn, w_out, b_out, (float*)d_out, nullptr, nullptr, 4096, 1024, 1024);
}